// Round 6
// baseline (279.451 us; speedup 1.0000x reference)
//
#include <hip/hip_runtime.h>
#include <cstdint>
#include <cmath>

#define V_SIZE 50257
#define T_SIZE 2048
#define B_SIZE 512
#define CHUNKS 8
#define CHUNK_ELEMS ((V_SIZE + CHUNKS - 1) / CHUNKS)   // 6283
#define NTHR_A 256
#define NTHR_B 512
#define NWAVE_B (NTHR_B / 64)
#define BCAP 128                                       // per-chunk collect cap
#define CAP (CHUNKS * BCAP)                            // 1024 -> no drops ever
#define SPEC_THRESH 10.0f
#define SPEC_MIN 80
#define KOFF 32.0f

// ws layout: gZ[512] f | gcnt[512] i | gbad[512] i | gval[512*CAP] f | gidx[512*CAP] i

// ---------------- Kernel A: copy-like read stream ----------------
// Per element: exp-accumulate + rare LDS-atomic collect (lgkm only; global
// loads never drained -- the R4 poison was the per-lane GLOBAL atomic return).
// Block epilogue: one global float atomicAdd (no return) for Z, one
// reservation atomicAdd for the candidate range, coalesced flush.
extern "C" __global__ __launch_bounds__(NTHR_A, 8)
void stream_kernel(const float* __restrict__ logits,
                   float* __restrict__ gZ, int* __restrict__ gcnt,
                   int* __restrict__ gbad,
                   float* __restrict__ gval, int* __restrict__ gidx)
{
    const int row  = blockIdx.y;
    const int tid  = threadIdx.x;
    const int lane = tid & 63;
    const int wid  = tid >> 6;

    __shared__ float bval[BCAP];
    __shared__ int   bidx[BCAP];
    __shared__ int   bcnt;
    __shared__ int   sBase;
    __shared__ float redz[NTHR_A / 64];
    if (tid == 0) bcnt = 0;
    __syncthreads();

    const size_t rowoff = (size_t)row * V_SIZE;
    const float* lrow = logits + rowoff;
    const int lo = blockIdx.x * CHUNK_ELEMS;
    const int hi = min(V_SIZE, lo + CHUNK_ELEMS);

    // global element g is 16B-aligned when (rowoff+g)%4==0 (V%4==1)
    int a0 = lo + (int)((4u - ((unsigned)((rowoff + lo) & 3u))) & 3u);
    if (a0 > hi) a0 = hi;
    const int nv = (hi - a0) >> 2;
    const int t0 = a0 + nv * 4;

    float lz = 0.0f;
    auto proc = [&](float x, int v) {
        lz += __expf(x - KOFF);                 // x <= ~20 -> no overflow
        if (x > SPEC_THRESH) {
            int p = atomicAdd(&bcnt, 1);        // LDS atomic: lgkm only
            if (p < BCAP) { bval[p] = x; bidx[p] = v; }
        }
    };
    if (tid < a0 - lo) proc(lrow[lo + tid], lo + tid);
    if (tid < hi - t0) proc(lrow[t0 + tid], t0 + tid);

    const float4* l4 = (const float4*)(lrow + a0);
    auto proc4 = [&](float4 x4, int v) {
        proc(x4.x, v); proc(x4.y, v + 1); proc(x4.z, v + 2); proc(x4.w, v + 3);
    };
    int i = tid;
    for (; i + 3 * NTHR_A < nv; i += 4 * NTHR_A) {
        float4 a = l4[i];
        float4 b = l4[i + NTHR_A];
        float4 c = l4[i + 2 * NTHR_A];
        float4 d = l4[i + 3 * NTHR_A];
        proc4(a, a0 + i * 4);
        proc4(b, a0 + (i + NTHR_A) * 4);
        proc4(c, a0 + (i + 2 * NTHR_A) * 4);
        proc4(d, a0 + (i + 3 * NTHR_A) * 4);
    }
    for (; i < nv; i += NTHR_A) {
        float4 a = l4[i];
        proc4(a, a0 + i * 4);
    }

    // block Z reduce -> single fire-and-forget global atomic
    for (int off = 32; off; off >>= 1) lz += __shfl_down(lz, off);
    if (lane == 0) redz[wid] = lz;
    __syncthreads();                            // also orders bcnt/bval/bidx
    if (tid == 0) {
        float s = 0.0f;
        for (int j = 0; j < NTHR_A / 64; ++j) s += redz[j];
        atomicAdd(&gZ[row], s);
        int c = bcnt;
        if (c > BCAP) { gbad[row] = 1; c = BCAP; }
        sBase = atomicAdd(&gcnt[row], c);       // sum <= 8*128 = CAP: no drops
    }
    __syncthreads();
    const int c    = min(bcnt, BCAP);
    const int base = sBase;
    for (int j = tid; j < c; j += NTHR_A) {
        gval[(size_t)row * CAP + base + j] = bval[j];
        gidx[(size_t)row * CAP + base + j] = bidx[j];
    }
}

// ---------------- Kernel B: per-row tail ----------------
extern "C" __global__ __launch_bounds__(NTHR_B, 4)
void tail_kernel(const float* __restrict__ logits,
                 const int*   __restrict__ prev,
                 const float* __restrict__ rand_u,
                 const float* __restrict__ tempp,
                 const float* __restrict__ toppp,
                 const float* __restrict__ repp,
                 const float* __restrict__ gZ,
                 const int*   __restrict__ gcnt,
                 const int*   __restrict__ gbad,
                 const float* __restrict__ gval,
                 const int*   __restrict__ gidx,
                 float* __restrict__ out)
{
    const int row  = blockIdx.x;
    const int tid  = threadIdx.x;
    const int lane = tid & 63;
    const int wid  = tid >> 6;

    __shared__ unsigned int bitmap[(V_SIZE + 31) / 32];
    __shared__ float cval[CAP];
    __shared__ int   cidx[CAP];
    __shared__ float rbuf[CAP];
    __shared__ float redf[NWAVE_B];
    __shared__ int   redi[NWAVE_B];
    __shared__ float sZ, sS;
    __shared__ int   sCnt, sSend, sGT;

    const float rp   = repp[0];
    const float topp = toppp[0];
    const float temp = fmaxf(tempp[0], 1e-5f);

    const size_t rowoff = (size_t)row * V_SIZE;
    const float* lrow = logits + rowoff;
    const float* urow = rand_u + rowoff;
    float*       orow = out + B_SIZE + rowoff;

    for (int i = tid; i < (V_SIZE + 31) / 32; i += NTHR_B) bitmap[i] = 0u;
    if (tid == 0) { sCnt = 0; sGT = 0; }
    __syncthreads();

    // prev bitmap + dedup Z-correction: dz = sum exp(pen(x)-K) - exp(x-K)
    float dz = 0.0f;
    const int4* prow4 = (const int4*)(prev + (size_t)row * T_SIZE);
    auto corr = [&](int t) {
        unsigned m = 1u << (t & 31);
        unsigned old = atomicOr(&bitmap[((unsigned)t) >> 5], m);
        if (!(old & m)) {                        // first setter owns this token
            float x = lrow[t];
            float y = (x < 0.0f) ? x * rp : x / rp;
            dz += __expf(y - KOFF) - __expf(x - KOFF);
        }
    };
    for (int j = tid; j < T_SIZE / 4; j += NTHR_B) {
        int4 t = prow4[j];
        corr(t.x); corr(t.y); corr(t.z); corr(t.w);
    }
    {
        for (int off = 32; off; off >>= 1) dz += __shfl_down(dz, off);
        if (lane == 0) redf[wid] = dz;
    }
    __syncthreads();
    if (tid == 0) {
        float s = 0.0f;
        for (int j = 0; j < NWAVE_B; ++j) s += redf[j];
        sZ = gZ[row] + s;                        // Z in K-offset form (exact)
    }
    __syncthreads();
    const float Z = sZ;

    // load candidates from ws, penalize, count penalized > 10
    const int cntg = gcnt[row];
    const int Craw = min(cntg, CAP);
    {
        int myGT = 0;
        for (int j = tid; j < Craw; j += NTHR_B) {
            float x = gval[(size_t)row * CAP + j];
            int   v = gidx[(size_t)row * CAP + j];
            if ((bitmap[((unsigned)v) >> 5] >> (v & 31)) & 1u)
                x = (x < 0.0f) ? x * rp : x / rp;
            cval[j] = x; cidx[j] = v;
            if (x > SPEC_THRESH) myGT++;
        }
        for (int off = 32; off; off >>= 1) myGT += __shfl_down(myGT, off);
        if (lane == 0) redi[wid] = myGT;
    }
    __syncthreads();
    if (tid == 0) {
        int s = 0;
        for (int j = 0; j < NWAVE_B; ++j) s += redi[j];
        sGT = s;
    }
    __syncthreads();

    // validity: pen<=raw (rp>=1) -> {raw>10} superset of {pen>10}; if >=80
    // penalized candidates exceed 10, the decision never leaves the set.
    const bool fb = (gbad[row] != 0) || (cntg < SPEC_MIN) || (cntg > CAP) ||
                    (sGT < SPEC_MIN) || (rp < 1.0f);
    int C;
    if (!fb) {
        C = Craw;
    } else {
        auto pen_at = [&](int v) {
            float x = lrow[v];
            if ((bitmap[((unsigned)v) >> 5] >> (v & 31)) & 1u)
                x = (x < 0.0f) ? x * rp : x / rp;
            return x;
        };
        auto count_pass = [&](float thr) -> int {
            __syncthreads();
            if (tid == 0) sCnt = 0;
            __syncthreads();
            int local = 0;
            for (int v = tid; v < V_SIZE; v += NTHR_B)
                if (pen_at(v) > thr) local++;
            if (local) atomicAdd(&sCnt, local);
            __syncthreads();
            return sCnt;
        };
        float a = -200.0f, b = 200.0f, thr = 0.0f;
        int c = 0;
        for (int it = 0; it < 40; ++it) {
            thr = 0.5f * (a + b);
            c = count_pass(thr);
            if (c < SPEC_MIN)      b = thr;
            else if (c > CAP)      a = thr;
            else break;
        }
        if (c < SPEC_MIN) thr = a;
        __syncthreads();
        if (tid == 0) sCnt = 0;
        __syncthreads();
        for (int v = tid; v < V_SIZE; v += NTHR_B) {
            float x = pen_at(v);
            if (x > thr) {
                int p = atomicAdd(&sCnt, 1);
                if (p < CAP) { cval[p] = x; cidx[p] = v; }
            }
        }
        __syncthreads();
        C = min(sCnt, CAP);
    }

    // bitonic sort: descending value, tie -> ascending index
    int n = 1; while (n < C) n <<= 1;
    for (int j = C + tid; j < n; j += NTHR_B) { cval[j] = -INFINITY; cidx[j] = 0x7FFFFFFF; }
    __syncthreads();
    for (int k = 2; k <= n; k <<= 1) {
        for (int j = k >> 1; j > 0; j >>= 1) {
            for (int p = tid; p < n; p += NTHR_B) {
                int l = p ^ j;
                if (l > p) {
                    float vi = cval[p], vl = cval[l];
                    int   ii = cidx[p], il = cidx[l];
                    bool lFirst = (vl > vi) || (vl == vi && il < ii);
                    bool asc = ((p & k) == 0);
                    if (lFirst == asc) {
                        cval[p] = vl; cval[l] = vi;
                        cidx[p] = il; cidx[l] = ii;
                    }
                }
            }
            __syncthreads();
        }
    }

    // serial decision: top-p prefix m, top-50 pivot tie-run e
    if (tid == 0) {
        float cum = 0.0f;
        int m = 0;
        float vp = cval[min(49, C - 1)];
        for (int j = 0; j < C; ++j) {
            cum += expf(cval[j] - KOFF) / Z;
            if (j > 0 && cum > topp) break;
            m = j;
            if (m >= 49 && cval[j] < vp) break;
        }
        int send;
        if (m >= 49) {
            int e = 49;
            while (e + 1 < C && cval[e + 1] == vp) ++e;
            send = (m < e) ? m : e;
        } else {
            send = m;
        }
        sSend = send;
    }
    __syncthreads();

    // final softmax over support (temperature), scatter probs, Gumbel argmax
    const int send = sSend;
    const float v0 = cval[0];
    for (int j = tid; j <= send; j += NTHR_B)
        rbuf[j] = expf(cval[j] / temp - v0 / temp);
    __syncthreads();
    if (tid == 0) {
        float S = 0.0f;
        for (int j = 0; j <= send; ++j) S += rbuf[j];
        sS = S;
    }
    __syncthreads();
    const float S = sS;

    float bestr = -1.0f;
    int   besti = 0x7FFFFFFF;
    for (int j = tid; j <= send; j += NTHR_B) {
        float p = rbuf[j] / S;
        int v = cidx[j];
        orow[v] = p;                             // memset zeroed the rest
        float q = -logf(urow[v]);
        float r = p / q;
        if (r > bestr || (r == bestr && v < besti)) { bestr = r; besti = v; }
    }
    for (int off = 32; off; off >>= 1) {
        float r2 = __shfl_down(bestr, off);
        int   i2 = __shfl_down(besti, off);
        if (r2 > bestr || (r2 == bestr && i2 < besti)) { bestr = r2; besti = i2; }
    }
    if (lane == 0) { redf[wid] = bestr; redi[wid] = besti; }
    __syncthreads();
    if (tid == 0) {
        float br = redf[0]; int bi = redi[0];
        for (int j = 1; j < NWAVE_B; ++j) {
            if (redf[j] > br || (redf[j] == br && redi[j] < bi)) { br = redf[j]; bi = redi[j]; }
        }
        out[row] = (float)bi;
    }
}

extern "C" void kernel_launch(void* const* d_in, const int* in_sizes, int n_in,
                              void* d_out, int out_size, void* d_ws, size_t ws_size,
                              hipStream_t stream) {
    const float* logits = (const float*)d_in[0];
    const int*   prev   = (const int*)d_in[1];
    const float* rand_u = (const float*)d_in[2];
    const float* tempp  = (const float*)d_in[3];
    const float* toppp  = (const float*)d_in[4];
    const float* repp   = (const float*)d_in[5];
    float* out = (float*)d_out;

    float* gZ   = (float*)d_ws;
    int*   gcnt = (int*)d_ws + B_SIZE;
    int*   gbad = (int*)d_ws + 2 * B_SIZE;
    float* gval = (float*)d_ws + 3 * B_SIZE;
    int*   gidx = (int*)d_ws + 3 * B_SIZE + B_SIZE * CAP;

    hipMemsetAsync(d_out, 0, (size_t)out_size * sizeof(float), stream);
    hipMemsetAsync(d_ws, 0, 3 * B_SIZE * sizeof(float), stream);

    hipLaunchKernelGGL(stream_kernel, dim3(CHUNKS, B_SIZE), dim3(NTHR_A), 0, stream,
                       logits, gZ, gcnt, gbad, gval, gidx);
    hipLaunchKernelGGL(tail_kernel, dim3(B_SIZE), dim3(NTHR_B), 0, stream,
                       logits, prev, rand_u, tempp, toppp, repp,
                       gZ, gcnt, gbad, gval, gidx, out);
}